// Round 1
// 4003.027 us; speedup vs baseline: 1.0583x; 1.0583x over previous
//
#include <hip/hip_runtime.h>
#include <cstddef>

// ---------------------------------------------------------------------------
// RelGraphConv GNN, 10 layers. Round 9: parallel CSR scan.
//   msg = b + W_loop x + sum_r W_r (segsum_r x)  computed as:
//     pass0: Z = x @ [W_0..W_3 | W_loop] (N x 640, dense MFMA GEMM)
//            seg0: msg[d] = b + Z[d,512:640] + sum_{e->d, r<4} Z[src_e, r*128:+128]
//     pass1: Z = x @ [W_4..W_7] (N x 512)
//            seg1: msg[d] += sum_{e->d, r>=4} Z[src_e, (r-4)*128:+128]
//   segsum: dst-sorted CSR, one 16-lane group per dst row — no atomics, no
//   LDS, no barriers, full occupancy.
//   Round 9: k_scan_row (single-block serial scan, 231 us, VALUBusy 0.01%,
//   occupancy 0.05%) replaced by 3-kernel hierarchical scan
//   (part/mid/fin, 256 blocks) — predicted <15 us total.
// Z buffer (128 MB) aliases mid (dead during Z/segsum); ws ~214 MB.
// N=100000, E=600000, F=64, H=128, R=8.
// ---------------------------------------------------------------------------

#define HID 128
#define NREL 8
#define NL 10

typedef __attribute__((ext_vector_type(8))) __bf16 bf16x8;
typedef __attribute__((ext_vector_type(4))) float f32x4;

// --- batched transpose + f32->bf16: tile z: W[zi][K][Nc] -> Wt[zo][Nc][K] ---
// zi = (z/inDiv)*inScale + z%inDiv + inOff ; zo likewise.
__global__ __launch_bounds__(256) void k_transpose(const float* __restrict__ W,
                                                   __bf16* __restrict__ Wt,
                                                   int K, int Nc,
                                                   int inDiv, int inScale, int inOff,
                                                   int outDiv, int outScale, int outOff) {
  __shared__ float t[32][33];
  int z = blockIdx.z;
  int zi = (z / inDiv) * inScale + (z % inDiv) + inOff;
  int zo = (z / outDiv) * outScale + (z % outDiv) + outOff;
  const float* Wz = W + (size_t)zi * K * Nc;
  __bf16* Wtz = Wt + (size_t)zo * K * Nc;
  int n0 = blockIdx.x * 32, k0 = blockIdx.y * 32;
#pragma unroll
  for (int i = 0; i < 4; i++) {
    int k = k0 + threadIdx.y + i * 8;
    int n = n0 + threadIdx.x;
    t[threadIdx.y + i * 8][threadIdx.x] = Wz[(size_t)k * Nc + n];
  }
  __syncthreads();
#pragma unroll
  for (int i = 0; i < 4; i++) {
    int n = n0 + threadIdx.y + i * 8;
    int k = k0 + threadIdx.x;
    Wtz[(size_t)n * K + k] = (__bf16)t[threadIdx.x][threadIdx.y + i * 8];
  }
}

// --- f32 -> bf16 elementwise (n4 = count/4) ---
__global__ __launch_bounds__(256) void k_cvt(const float* __restrict__ x,
                                             __bf16* __restrict__ y, int n4) {
  int i = blockIdx.x * 256 + threadIdx.x;
  if (i < n4) {
    float4 f = ((const float4*)x)[i];
    __bf16 o[4] = {(__bf16)f.x, (__bf16)f.y, (__bf16)f.z, (__bf16)f.w};
    *(uint2*)(y + (size_t)i * 4) = *(uint2*)o;
  }
}

// ===================== dst-CSR build (once per launch) ======================
__global__ __launch_bounds__(256) void k_zero(int* __restrict__ p, int n) {
  for (int i = blockIdx.x * 256 + threadIdx.x; i < n; i += gridDim.x * 256) p[i] = 0;
}

__global__ __launch_bounds__(256) void k_hist_row(const int* __restrict__ dst,
                                                  int E, int* __restrict__ rowCnt) {
  int e = blockIdx.x * 256 + threadIdx.x;
  if (e < E) atomicAdd(&rowCnt[dst[e]], 1);
}

// --- hierarchical prefix scan over rowCnt[0..nb) -----------------------------
// part: per-thread chunk sum, block-level Hillis-Steele exclusive scan,
//       per-block total. 256 blocks x 256 threads -> chunk = 2 rows/thread.
__global__ __launch_bounds__(256) void k_scan_part(const int* __restrict__ rowCnt,
                                                   int nb, int* __restrict__ thrPre,
                                                   int* __restrict__ blkSum) {
  __shared__ int sdata[256];
  int tid = threadIdx.x;
  int gtid = blockIdx.x * 256 + tid;
  int tot = gridDim.x * 256;
  int chunk = (nb + tot - 1) / tot;
  int lo = gtid * chunk, hi = min(nb, lo + chunk);
  int s = 0;
  for (int i = lo; i < hi; i++) s += rowCnt[i];
  sdata[tid] = s;
  __syncthreads();
#pragma unroll
  for (int off = 1; off < 256; off <<= 1) {
    int t = (tid >= off) ? sdata[tid - off] : 0;
    __syncthreads();
    sdata[tid] += t;
    __syncthreads();
  }
  thrPre[gtid] = sdata[tid] - s;  // exclusive prefix within block
  if (tid == 255) blkSum[blockIdx.x] = sdata[255];
}

// mid: scan the (<=256) block totals; write rowStart[nb] = total.
__global__ __launch_bounds__(256) void k_scan_mid(const int* __restrict__ blkSum,
                                                  int nblk, int nb,
                                                  int* __restrict__ blkOff,
                                                  int* __restrict__ rowStart) {
  __shared__ int part[256];
  int tid = threadIdx.x;
  part[tid] = (tid < nblk) ? blkSum[tid] : 0;
  __syncthreads();
  if (tid == 0) {
    int a = 0;
    for (int i = 0; i < nblk; i++) { int v = part[i]; part[i] = a; a += v; }
    rowStart[nb] = a;
  }
  __syncthreads();
  if (tid < nblk) blkOff[tid] = part[tid];
}

// fin: rowStart/rowCur from blkOff + thrPre + local rescan of the chunk.
__global__ __launch_bounds__(256) void k_scan_fin(const int* __restrict__ rowCnt,
                                                  int nb,
                                                  const int* __restrict__ thrPre,
                                                  const int* __restrict__ blkOff,
                                                  int* __restrict__ rowStart,
                                                  int* __restrict__ rowCur) {
  int tid = threadIdx.x;
  int gtid = blockIdx.x * 256 + tid;
  int tot = gridDim.x * 256;
  int chunk = (nb + tot - 1) / tot;
  int lo = gtid * chunk, hi = min(nb, lo + chunk);
  int run = blkOff[blockIdx.x] + thrPre[gtid];
  for (int i = lo; i < hi; i++) {
    rowStart[i] = run;
    rowCur[i] = run;
    run += rowCnt[i];
  }
}

// pack: src (17 bits) | etype << 17
__global__ __launch_bounds__(256) void k_place_row(const int* __restrict__ et,
                                                   const int* __restrict__ src,
                                                   const int* __restrict__ dst,
                                                   int* __restrict__ rowCur,
                                                   int* __restrict__ epk, int E) {
  int e = blockIdx.x * 256 + threadIdx.x;
  if (e < E) {
    int p = atomicAdd(&rowCur[dst[e]], 1);
    epk[p] = src[e] | (et[e] << 17);
  }
}

// ========================= CSR segment-sum kernel ===========================
// 16 lanes per dst row (lane covers 8 of 128 features), 16 rows per block.
// No LDS, no atomics: each row owned by exactly one lane-group.
// selfCol >= 0 (pass 0): acc = b_rel + Z[d][selfCol..]; else acc = msgb[d].
__global__ __launch_bounds__(256) void seg_sum(
    const __bf16* __restrict__ Z, const int* __restrict__ rowStart,
    const int* __restrict__ epk, const float* __restrict__ b_rel_l,
    __bf16* __restrict__ msgb, int N, int relBase, int zW, int selfCol) {
  int t16 = threadIdx.x & 15;
  int d = blockIdx.x * 16 + (threadIdx.x >> 4);
  if (d >= N) return;

  float acc[8];
  if (selfCol >= 0) {
    bf16x8 sv = *(const bf16x8*)(Z + (size_t)d * zW + selfCol + t16 * 8);
#pragma unroll
    for (int z = 0; z < 8; z++) acc[z] = (float)sv[z] + b_rel_l[t16 * 8 + z];
  } else {
    bf16x8 mv = *(const bf16x8*)(msgb + (size_t)d * HID + t16 * 8);
#pragma unroll
    for (int z = 0; z < 8; z++) acc[z] = (float)mv[z];
  }

  int lo = rowStart[d], hi = rowStart[d + 1];
  for (int e = lo; e < hi; e++) {
    int p = epk[e];
    int rr = (p >> 17) - relBase;
    if ((unsigned)rr < 4u) {
      bf16x8 v = *(const bf16x8*)(Z + (size_t)(p & 0x1FFFF) * zW + rr * HID + t16 * 8);
#pragma unroll
      for (int z = 0; z < 8; z++) acc[z] += (float)v[z];
    }
  }

  bf16x8 o;
#pragma unroll
  for (int z = 0; z < 8; z++) o[z] = (__bf16)acc[z];
  *(bf16x8*)(msgb + (size_t)d * HID + t16 * 8) = o;
}

// ---------------------------------------------------------------------------
// bf16 MFMA GEMM (dense): C = act(concat(A0,A1) @ B + bias)   [proven]
// ---------------------------------------------------------------------------
__global__ __launch_bounds__(256) void gemm_bf16(
    const __bf16* __restrict__ A0, const void* __restrict__ A1v, int a1_f32,
    int K0, int K,
    const __bf16* __restrict__ Bt, const float* __restrict__ bias,
    __bf16* __restrict__ Cb, float* __restrict__ Cf,
    int M, int Nc, int act) {
  __shared__ __bf16 As[128][72];
  __shared__ __bf16 Bs[128][72];
  const int tid = threadIdx.x;
  const int m0 = blockIdx.x * 128;
  const int bn0 = blockIdx.y * 128;
  const int lane = tid & 63;
  const int w = tid >> 6;
  const int ml = lane & 15, q = lane >> 4;
  const int wr = (w >> 1) * 64, wc = (w & 1) * 64;
  const int KA1 = K - K0;

  f32x4 acc[4][4];
#pragma unroll
  for (int i = 0; i < 4; i++)
#pragma unroll
    for (int j = 0; j < 4; j++)
#pragma unroll
      for (int r = 0; r < 4; r++) acc[i][j][r] = 0.f;

  for (int k0 = 0; k0 < K; k0 += 64) {
#pragma unroll
    for (int i = 0; i < 4; i++) {
      int ci = tid + i * 256;
      int row = ci >> 3;
      int kc = ci & 7;
      int gk = k0 + kc * 8;
      int gr = m0 + row;
      bf16x8 va;
#pragma unroll
      for (int z = 0; z < 8; z++) va[z] = (__bf16)0.f;
      if (gr < M) {
        if (gk < K0) {
          va = *(const bf16x8*)(A0 + (size_t)gr * K0 + gk);
        } else if (!a1_f32) {
          va = *(const bf16x8*)((const __bf16*)A1v + (size_t)gr * KA1 + (gk - K0));
        } else {
          const float* p = (const float*)A1v + (size_t)gr * KA1 + (gk - K0);
          float4 f0 = *(const float4*)p;
          float4 f1 = *(const float4*)(p + 4);
          va[0] = (__bf16)f0.x; va[1] = (__bf16)f0.y;
          va[2] = (__bf16)f0.z; va[3] = (__bf16)f0.w;
          va[4] = (__bf16)f1.x; va[5] = (__bf16)f1.y;
          va[6] = (__bf16)f1.z; va[7] = (__bf16)f1.w;
        }
      }
      *(bf16x8*)(&As[row][kc * 8]) = va;
      bf16x8 vb = *(const bf16x8*)(Bt + (size_t)(bn0 + row) * K + gk);
      *(bf16x8*)(&Bs[row][kc * 8]) = vb;
    }
    __syncthreads();
#pragma unroll
    for (int kk = 0; kk < 2; kk++) {
      bf16x8 af[4], bfr[4];
#pragma unroll
      for (int i = 0; i < 4; i++)
        af[i] = *(const bf16x8*)(&As[wr + i * 16 + ml][kk * 32 + q * 8]);
#pragma unroll
      for (int j = 0; j < 4; j++)
        bfr[j] = *(const bf16x8*)(&Bs[wc + j * 16 + ml][kk * 32 + q * 8]);
#pragma unroll
      for (int i = 0; i < 4; i++)
#pragma unroll
        for (int j = 0; j < 4; j++)
          acc[i][j] = __builtin_amdgcn_mfma_f32_16x16x32_bf16(af[i], bfr[j],
                                                              acc[i][j], 0, 0, 0);
    }
    __syncthreads();
  }

#pragma unroll
  for (int i = 0; i < 4; i++) {
#pragma unroll
    for (int r = 0; r < 4; r++) {
      int grow = m0 + wr + i * 16 + q * 4 + r;
      if (grow >= M) continue;
#pragma unroll
      for (int j = 0; j < 4; j++) {
        int col = bn0 + wc + j * 16 + ml;
        float v = acc[i][j][r];
        if (bias) v += bias[col];
        if (act) v = tanhf(v);
        if (Cb) Cb[(size_t)grow * Nc + col] = (__bf16)v;
        if (Cf) Cf[(size_t)grow * Nc + col] = v;
      }
    }
  }
}

extern "C" void kernel_launch(void* const* d_in, const int* in_sizes, int n_in,
                              void* d_out, int out_size, void* d_ws, size_t ws_size,
                              hipStream_t stream) {
  const float* feats  = (const float*)d_in[0];
  const int*   src    = (const int*)d_in[1];
  const int*   dst    = (const int*)d_in[2];
  const int*   etype  = (const int*)d_in[3];
  const float* W_in   = (const float*)d_in[4];
  const float* b_in   = (const float*)d_in[5];
  const float* W_rel  = (const float*)d_in[6];
  const float* W_loop = (const float*)d_in[7];
  const float* b_rel  = (const float*)d_in[8];
  const float* W_u1   = (const float*)d_in[9];
  const float* b_u1   = (const float*)d_in[10];
  const float* W_u2   = (const float*)d_in[11];
  const float* b_u2   = (const float*)d_in[12];

  const int E = in_sizes[1];
  const int N = in_sizes[0] / 64;
  const int TS = HID * HID;  // 16384 elems per weight tile

  // --- workspace layout (~214 MB) ---
  __bf16* xb0  = (__bf16*)d_ws;                       // N*128
  __bf16* xb1  = xb0 + (size_t)N * HID;               // N*128
  __bf16* msgb = xb1 + (size_t)N * HID;               // N*128
  __bf16* U    = msgb + (size_t)N * HID;              // N*640 (Z | mid | featsb)
  __bf16* Z    = U;
  __bf16* mid  = U;
  __bf16* featsb = U;
  __bf16* wt_in = U + (size_t)N * 640;                // [128][64]
  __bf16* wt_z0 = wt_in + 128 * 64;                   // [10][5][128][128]
  __bf16* wt_z1 = wt_z0 + (size_t)10 * 5 * TS;        // [10][4][128][128]
  __bf16* wt_u1 = wt_z1 + (size_t)10 * 4 * TS;        // [10][256][256]
  __bf16* wt_u2 = wt_u1 + (size_t)10 * 256 * 256;     // [10][128][384]
  int* rowCnt   = (int*)(wt_u2 + (size_t)10 * 128 * 384); // N
  int* rowStart = rowCnt + N;                         // N+1
  int* rowCur   = rowStart + N + 1;                   // N
  int* epk      = rowCur + N;                         // E
  int* thrPre   = epk + E;                            // 256*256 = 65536
  int* blkSum   = thrPre + 256 * 256;                 // 256
  int* blkOff   = blkSum + 256;                       // 256

  // --- weight transpose+convert ---
  // W_in -> wt_in
  k_transpose<<<dim3(4, 2, 1), dim3(32, 8), 0, stream>>>(W_in, wt_in, 64, 128,
                                                         1, 1, 0, 1, 1, 0);
  // W_rel r<4 -> wt_z0 tiles (l*5 + r)
  k_transpose<<<dim3(4, 4, 40), dim3(32, 8), 0, stream>>>(W_rel, wt_z0, 128, 128,
                                                          4, 8, 0, 4, 5, 0);
  // W_rel r>=4 -> wt_z1 tiles (l*4 + r-4)
  k_transpose<<<dim3(4, 4, 40), dim3(32, 8), 0, stream>>>(W_rel, wt_z1, 128, 128,
                                                          4, 8, 4, 4, 4, 0);
  // W_loop -> wt_z0 tile (l*5 + 4)
  k_transpose<<<dim3(4, 4, 10), dim3(32, 8), 0, stream>>>(W_loop, wt_z0, 128, 128,
                                                          1, 1, 0, 1, 5, 4);
  // W_u1, W_u2
  k_transpose<<<dim3(8, 8, 10), dim3(32, 8), 0, stream>>>(W_u1, wt_u1, 256, 256,
                                                          1, 1, 0, 1, 1, 0);
  k_transpose<<<dim3(4, 12, 10), dim3(32, 8), 0, stream>>>(W_u2, wt_u2, 384, 128,
                                                           1, 1, 0, 1, 1, 0);
  k_cvt<<<(N * 64 / 4 + 255) / 256, 256, 0, stream>>>(feats, featsb, N * 64 / 4);

  // --- dst-CSR build (once; graph is layer-invariant) ---
  k_zero<<<128, 256, 0, stream>>>(rowCnt, N);
  k_hist_row<<<(E + 255) / 256, 256, 0, stream>>>(dst, E, rowCnt);
  // hierarchical scan (replaces single-block k_scan_row, was 231 us)
  k_scan_part<<<256, 256, 0, stream>>>(rowCnt, N, thrPre, blkSum);
  k_scan_mid<<<1, 256, 0, stream>>>(blkSum, 256, N, blkOff, rowStart);
  k_scan_fin<<<256, 256, 0, stream>>>(rowCnt, N, thrPre, blkOff, rowStart, rowCur);
  k_place_row<<<(E + 255) / 256, 256, 0, stream>>>(etype, src, dst, rowCur, epk, E);

  const dim3 blk(256);
  const int gm = (N + 127) / 128;
  const dim3 gseg((N + 15) / 16);

  // input projection: x0 = tanh(featsb @ W_in + b_in)  (featsb inside U: ok,
  // this GEMM writes xb0 only)
  gemm_bf16<<<dim3(gm, 1), blk, 0, stream>>>(featsb, nullptr, 0, 64, 64, wt_in,
                                             b_in, xb0, nullptr, N, HID, 1);

  for (int l = 0; l < NL; l++) {
    const __bf16* xin = (l & 1) ? xb1 : xb0;
    __bf16* xout = (l & 1) ? xb0 : xb1;

    // pass 0: Z = xin @ [W_0..3 | W_loop]  (N x 640)
    gemm_bf16<<<dim3(gm, 5), blk, 0, stream>>>(xin, nullptr, 0, HID, HID,
                                               wt_z0 + (size_t)l * 5 * TS,
                                               nullptr, Z, nullptr, N, 640, 0);
    // seg0: msg = b + Z_self + sum(r<4) edges
    seg_sum<<<gseg, blk, 0, stream>>>(Z, rowStart, epk, b_rel + (size_t)l * HID,
                                      msgb, N, 0, 640, 512);
    // pass 1: Z = xin @ [W_4..7]  (N x 512)
    gemm_bf16<<<dim3(gm, 4), blk, 0, stream>>>(xin, nullptr, 0, HID, HID,
                                               wt_z1 + (size_t)l * 4 * TS,
                                               nullptr, Z, nullptr, N, 512, 0);
    // seg1: msg += sum(r>=4) edges
    seg_sum<<<gseg, blk, 0, stream>>>(Z, rowStart, epk, nullptr,
                                      msgb, N, 4, 512, -1);

    // mid = tanh([x | msg] @ W_u1[l] + b_u1[l])   (mid aliases Z; Z is dead)
    gemm_bf16<<<dim3(gm, 2), blk, 0, stream>>>(xin, msgb, 0, HID, 256,
                                               wt_u1 + (size_t)l * 256 * 256,
                                               b_u1 + (size_t)l * 256,
                                               mid, nullptr, N, 256, 1);

    // x' = tanh([x | mid] @ W_u2[l] + b_u2[l]); last layer -> f32 d_out
    gemm_bf16<<<dim3(gm, 1), blk, 0, stream>>>(xin, mid, 0, HID, 384,
                                               wt_u2 + (size_t)l * HID * 384,
                                               b_u2 + (size_t)l * HID,
                                               (l == NL - 1) ? nullptr : xout,
                                               (l == NL - 1) ? (float*)d_out : nullptr,
                                               N, HID, 1);
  }
}

// Round 2
// 3842.460 us; speedup vs baseline: 1.1025x; 1.0418x over previous
//
#include <hip/hip_runtime.h>
#include <cstddef>

// ---------------------------------------------------------------------------
// RelGraphConv GNN, 10 layers. Round 10: streaming B-resident GEMM.
//   All dense GEMMs (pass0/pass1/U1/U2/proj) were latency-bound at ~14% of
//   HBM BW (116 us for U1, MfmaUtil 4%, occupancy 17%): K<=384 means only
//   2-6 barrier-chopped K-chunks, so the pipeline never fills.
//   New gemm_stream<K,K0>: stage the full B column-tile (<=100 KB) in LDS
//   ONCE (one barrier), then stream A directly global->VGPR fragments with a
//   fully unrolled compile-time K-loop — no As LDS, no further barriers.
//   B re-fetch per block comes from L2 (B-tile <= 98 KB, L2-resident).
// Z buffer (128 MB) aliases mid (dead during Z/segsum); ws ~214 MB.
// N=100000, E=600000, F=64, H=128, R=8.
// ---------------------------------------------------------------------------

#define HID 128
#define NREL 8
#define NL 10

typedef __attribute__((ext_vector_type(8))) __bf16 bf16x8;
typedef __attribute__((ext_vector_type(4))) float f32x4;

// --- batched transpose + f32->bf16: tile z: W[zi][K][Nc] -> Wt[zo][Nc][K] ---
__global__ __launch_bounds__(256) void k_transpose(const float* __restrict__ W,
                                                   __bf16* __restrict__ Wt,
                                                   int K, int Nc,
                                                   int inDiv, int inScale, int inOff,
                                                   int outDiv, int outScale, int outOff) {
  __shared__ float t[32][33];
  int z = blockIdx.z;
  int zi = (z / inDiv) * inScale + (z % inDiv) + inOff;
  int zo = (z / outDiv) * outScale + (z % outDiv) + outOff;
  const float* Wz = W + (size_t)zi * K * Nc;
  __bf16* Wtz = Wt + (size_t)zo * K * Nc;
  int n0 = blockIdx.x * 32, k0 = blockIdx.y * 32;
#pragma unroll
  for (int i = 0; i < 4; i++) {
    int k = k0 + threadIdx.y + i * 8;
    int n = n0 + threadIdx.x;
    t[threadIdx.y + i * 8][threadIdx.x] = Wz[(size_t)k * Nc + n];
  }
  __syncthreads();
#pragma unroll
  for (int i = 0; i < 4; i++) {
    int n = n0 + threadIdx.y + i * 8;
    int k = k0 + threadIdx.x;
    Wtz[(size_t)n * K + k] = (__bf16)t[threadIdx.x][threadIdx.y + i * 8];
  }
}

// --- f32 -> bf16 elementwise (n4 = count/4) ---
__global__ __launch_bounds__(256) void k_cvt(const float* __restrict__ x,
                                             __bf16* __restrict__ y, int n4) {
  int i = blockIdx.x * 256 + threadIdx.x;
  if (i < n4) {
    float4 f = ((const float4*)x)[i];
    __bf16 o[4] = {(__bf16)f.x, (__bf16)f.y, (__bf16)f.z, (__bf16)f.w};
    *(uint2*)(y + (size_t)i * 4) = *(uint2*)o;
  }
}

// ===================== dst-CSR build (once per launch) ======================
__global__ __launch_bounds__(256) void k_zero(int* __restrict__ p, int n) {
  for (int i = blockIdx.x * 256 + threadIdx.x; i < n; i += gridDim.x * 256) p[i] = 0;
}

__global__ __launch_bounds__(256) void k_hist_row(const int* __restrict__ dst,
                                                  int E, int* __restrict__ rowCnt) {
  int e = blockIdx.x * 256 + threadIdx.x;
  if (e < E) atomicAdd(&rowCnt[dst[e]], 1);
}

// --- hierarchical prefix scan over rowCnt[0..nb) ---------------------------
__global__ __launch_bounds__(256) void k_scan_part(const int* __restrict__ rowCnt,
                                                   int nb, int* __restrict__ thrPre,
                                                   int* __restrict__ blkSum) {
  __shared__ int sdata[256];
  int tid = threadIdx.x;
  int gtid = blockIdx.x * 256 + tid;
  int tot = gridDim.x * 256;
  int chunk = (nb + tot - 1) / tot;
  int lo = gtid * chunk, hi = min(nb, lo + chunk);
  int s = 0;
  for (int i = lo; i < hi; i++) s += rowCnt[i];
  sdata[tid] = s;
  __syncthreads();
#pragma unroll
  for (int off = 1; off < 256; off <<= 1) {
    int t = (tid >= off) ? sdata[tid - off] : 0;
    __syncthreads();
    sdata[tid] += t;
    __syncthreads();
  }
  thrPre[gtid] = sdata[tid] - s;
  if (tid == 255) blkSum[blockIdx.x] = sdata[255];
}

__global__ __launch_bounds__(256) void k_scan_mid(const int* __restrict__ blkSum,
                                                  int nblk, int nb,
                                                  int* __restrict__ blkOff,
                                                  int* __restrict__ rowStart) {
  __shared__ int part[256];
  int tid = threadIdx.x;
  part[tid] = (tid < nblk) ? blkSum[tid] : 0;
  __syncthreads();
  if (tid == 0) {
    int a = 0;
    for (int i = 0; i < nblk; i++) { int v = part[i]; part[i] = a; a += v; }
    rowStart[nb] = a;
  }
  __syncthreads();
  if (tid < nblk) blkOff[tid] = part[tid];
}

__global__ __launch_bounds__(256) void k_scan_fin(const int* __restrict__ rowCnt,
                                                  int nb,
                                                  const int* __restrict__ thrPre,
                                                  const int* __restrict__ blkOff,
                                                  int* __restrict__ rowStart,
                                                  int* __restrict__ rowCur) {
  int tid = threadIdx.x;
  int gtid = blockIdx.x * 256 + tid;
  int tot = gridDim.x * 256;
  int chunk = (nb + tot - 1) / tot;
  int lo = gtid * chunk, hi = min(nb, lo + chunk);
  int run = blkOff[blockIdx.x] + thrPre[gtid];
  for (int i = lo; i < hi; i++) {
    rowStart[i] = run;
    rowCur[i] = run;
    run += rowCnt[i];
  }
}

// pack: src (17 bits) | etype << 17
__global__ __launch_bounds__(256) void k_place_row(const int* __restrict__ et,
                                                   const int* __restrict__ src,
                                                   const int* __restrict__ dst,
                                                   int* __restrict__ rowCur,
                                                   int* __restrict__ epk, int E) {
  int e = blockIdx.x * 256 + threadIdx.x;
  if (e < E) {
    int p = atomicAdd(&rowCur[dst[e]], 1);
    epk[p] = src[e] | (et[e] << 17);
  }
}

// ========================= CSR segment-sum kernel ===========================
__global__ __launch_bounds__(256) void seg_sum(
    const __bf16* __restrict__ Z, const int* __restrict__ rowStart,
    const int* __restrict__ epk, const float* __restrict__ b_rel_l,
    __bf16* __restrict__ msgb, int N, int relBase, int zW, int selfCol) {
  int t16 = threadIdx.x & 15;
  int d = blockIdx.x * 16 + (threadIdx.x >> 4);
  if (d >= N) return;

  float acc[8];
  if (selfCol >= 0) {
    bf16x8 sv = *(const bf16x8*)(Z + (size_t)d * zW + selfCol + t16 * 8);
#pragma unroll
    for (int z = 0; z < 8; z++) acc[z] = (float)sv[z] + b_rel_l[t16 * 8 + z];
  } else {
    bf16x8 mv = *(const bf16x8*)(msgb + (size_t)d * HID + t16 * 8);
#pragma unroll
    for (int z = 0; z < 8; z++) acc[z] = (float)mv[z];
  }

  int lo = rowStart[d], hi = rowStart[d + 1];
  for (int e = lo; e < hi; e++) {
    int p = epk[e];
    int rr = (p >> 17) - relBase;
    if ((unsigned)rr < 4u) {
      bf16x8 v = *(const bf16x8*)(Z + (size_t)(p & 0x1FFFF) * zW + rr * HID + t16 * 8);
#pragma unroll
      for (int z = 0; z < 8; z++) acc[z] += (float)v[z];
    }
  }

  bf16x8 o;
#pragma unroll
  for (int z = 0; z < 8; z++) o[z] = (__bf16)acc[z];
  *(bf16x8*)(msgb + (size_t)d * HID + t16 * 8) = o;
}

// ---------------------------------------------------------------------------
// Streaming bf16 MFMA GEMM: C = act(concat(A0,A1) @ B + bias)
//   B column-tile (128 cols x K) staged in LDS once; A streamed directly
//   global -> VGPR fragments; compile-time unrolled K loop; ONE barrier.
//   K, K0 compile-time; K0 % 32 == 0 so the A0/A1 split is loop-level.
//   LDS row pad +8 bf16 => row stride = 4 mod 32 banks (b128 reads at floor).
// ---------------------------------------------------------------------------
template <int K, int K0, int MINW>
__global__ __launch_bounds__(256, MINW) void gemm_stream(
    const __bf16* __restrict__ A0, const __bf16* __restrict__ A1,
    const __bf16* __restrict__ Bt, const float* __restrict__ bias,
    __bf16* __restrict__ Cb, float* __restrict__ Cf,
    int M, int Nc, int act) {
  constexpr int PK = K + 8;
  constexpr int K1 = K - K0;
  constexpr int NK0 = K0 / 32;
  constexpr int NK = K / 32;
  __shared__ __bf16 Bs[128][PK];

  const int tid = threadIdx.x;
  const int m0 = blockIdx.x * 128;
  const int bn0 = blockIdx.y * 128;

  // --- stage B column-tile: 128 rows (= output cols) x K ---
  {
    const int c8 = tid >> 3;            // 0..31
    const int kc = (tid & 7) * 8;       // 0,8,..,56
#pragma unroll
    for (int kb = 0; kb < K; kb += 64) {
#pragma unroll
      for (int cg = 0; cg < 128; cg += 32) {
        bf16x8 v = *(const bf16x8*)(Bt + (size_t)(bn0 + cg + c8) * K + kb + kc);
        *(bf16x8*)(&Bs[cg + c8][kb + kc]) = v;
      }
    }
  }

  const int lane = tid & 63;
  const int w = tid >> 6;
  const int ml = lane & 15, q = lane >> 4;
  const int wr = (w >> 1) * 64, wc = (w & 1) * 64;

  // per-i clamped row base pointers (clamp => always-valid loads, full MLP)
  const __bf16* pA0[4];
  const __bf16* pA1[4];
  int rowv[4];
#pragma unroll
  for (int i = 0; i < 4; i++) {
    int row = m0 + wr + i * 16 + ml;
    rowv[i] = row;
    int rc = row < M ? row : M - 1;
    pA0[i] = A0 + (size_t)rc * K0;
    if (K1 > 0) pA1[i] = A1 + (size_t)rc * K1;
  }

  f32x4 acc[4][4];
#pragma unroll
  for (int i = 0; i < 4; i++)
#pragma unroll
    for (int j = 0; j < 4; j++)
#pragma unroll
      for (int r = 0; r < 4; r++) acc[i][j][r] = 0.f;

  __syncthreads();  // B ready

  // --- A0 segment: k in [0, K0) ---
#pragma unroll
  for (int kk = 0; kk < NK0; kk++) {
    const int gk = kk * 32 + q * 8;
    bf16x8 af[4];
#pragma unroll
    for (int i = 0; i < 4; i++) af[i] = *(const bf16x8*)(pA0[i] + gk);
    bf16x8 bfr[4];
#pragma unroll
    for (int j = 0; j < 4; j++)
      bfr[j] = *(const bf16x8*)(&Bs[wc + j * 16 + ml][gk]);
#pragma unroll
    for (int i = 0; i < 4; i++)
#pragma unroll
      for (int j = 0; j < 4; j++)
        acc[i][j] = __builtin_amdgcn_mfma_f32_16x16x32_bf16(af[i], bfr[j],
                                                            acc[i][j], 0, 0, 0);
  }
  // --- A1 segment: k in [K0, K) ---
#pragma unroll
  for (int kk = NK0; kk < NK; kk++) {
    const int gk1 = (kk - NK0) * 32 + q * 8;       // offset within A1
    const int gk = kk * 32 + q * 8;                // offset within Bs
    bf16x8 af[4];
#pragma unroll
    for (int i = 0; i < 4; i++) af[i] = *(const bf16x8*)(pA1[i] + gk1);
    bf16x8 bfr[4];
#pragma unroll
    for (int j = 0; j < 4; j++)
      bfr[j] = *(const bf16x8*)(&Bs[wc + j * 16 + ml][gk]);
#pragma unroll
    for (int i = 0; i < 4; i++)
#pragma unroll
      for (int j = 0; j < 4; j++)
        acc[i][j] = __builtin_amdgcn_mfma_f32_16x16x32_bf16(af[i], bfr[j],
                                                            acc[i][j], 0, 0, 0);
  }

  // --- epilogue ---
#pragma unroll
  for (int i = 0; i < 4; i++) {
#pragma unroll
    for (int r = 0; r < 4; r++) {
      int grow = m0 + wr + i * 16 + q * 4 + r;
      if (grow >= M) continue;
#pragma unroll
      for (int j = 0; j < 4; j++) {
        int col = bn0 + wc + j * 16 + ml;
        float v = acc[i][j][r];
        if (bias) v += bias[col];
        if (act) v = tanhf(v);
        if (Cb) Cb[(size_t)grow * Nc + col] = (__bf16)v;
        if (Cf) Cf[(size_t)grow * Nc + col] = v;
      }
    }
  }
}

extern "C" void kernel_launch(void* const* d_in, const int* in_sizes, int n_in,
                              void* d_out, int out_size, void* d_ws, size_t ws_size,
                              hipStream_t stream) {
  const float* feats  = (const float*)d_in[0];
  const int*   src    = (const int*)d_in[1];
  const int*   dst    = (const int*)d_in[2];
  const int*   etype  = (const int*)d_in[3];
  const float* W_in   = (const float*)d_in[4];
  const float* b_in   = (const float*)d_in[5];
  const float* W_rel  = (const float*)d_in[6];
  const float* W_loop = (const float*)d_in[7];
  const float* b_rel  = (const float*)d_in[8];
  const float* W_u1   = (const float*)d_in[9];
  const float* b_u1   = (const float*)d_in[10];
  const float* W_u2   = (const float*)d_in[11];
  const float* b_u2   = (const float*)d_in[12];

  const int E = in_sizes[1];
  const int N = in_sizes[0] / 64;
  const int TS = HID * HID;

  // --- workspace layout (~214 MB) ---
  __bf16* xb0  = (__bf16*)d_ws;                       // N*128
  __bf16* xb1  = xb0 + (size_t)N * HID;               // N*128
  __bf16* msgb = xb1 + (size_t)N * HID;               // N*128
  __bf16* U    = msgb + (size_t)N * HID;              // N*640 (Z | mid | featsb)
  __bf16* Z    = U;
  __bf16* mid  = U;
  __bf16* featsb = U;
  __bf16* wt_in = U + (size_t)N * 640;                // [128][64]
  __bf16* wt_z0 = wt_in + 128 * 64;                   // [10][5][128][128]
  __bf16* wt_z1 = wt_z0 + (size_t)10 * 5 * TS;        // [10][4][128][128]
  __bf16* wt_u1 = wt_z1 + (size_t)10 * 4 * TS;        // [10][256][256]
  __bf16* wt_u2 = wt_u1 + (size_t)10 * 256 * 256;     // [10][128][384]
  int* rowCnt   = (int*)(wt_u2 + (size_t)10 * 128 * 384); // N
  int* rowStart = rowCnt + N;                         // N+1
  int* rowCur   = rowStart + N + 1;                   // N
  int* epk      = rowCur + N;                         // E
  int* thrPre   = epk + E;                            // 256*256
  int* blkSum   = thrPre + 256 * 256;                 // 256
  int* blkOff   = blkSum + 256;                       // 256

  // --- weight transpose+convert ---
  k_transpose<<<dim3(4, 2, 1), dim3(32, 8), 0, stream>>>(W_in, wt_in, 64, 128,
                                                         1, 1, 0, 1, 1, 0);
  k_transpose<<<dim3(4, 4, 40), dim3(32, 8), 0, stream>>>(W_rel, wt_z0, 128, 128,
                                                          4, 8, 0, 4, 5, 0);
  k_transpose<<<dim3(4, 4, 40), dim3(32, 8), 0, stream>>>(W_rel, wt_z1, 128, 128,
                                                          4, 8, 4, 4, 4, 0);
  k_transpose<<<dim3(4, 4, 10), dim3(32, 8), 0, stream>>>(W_loop, wt_z0, 128, 128,
                                                          1, 1, 0, 1, 5, 4);
  k_transpose<<<dim3(8, 8, 10), dim3(32, 8), 0, stream>>>(W_u1, wt_u1, 256, 256,
                                                          1, 1, 0, 1, 1, 0);
  k_transpose<<<dim3(4, 12, 10), dim3(32, 8), 0, stream>>>(W_u2, wt_u2, 384, 128,
                                                           1, 1, 0, 1, 1, 0);
  k_cvt<<<(N * 64 / 4 + 255) / 256, 256, 0, stream>>>(feats, featsb, N * 64 / 4);

  // --- dst-CSR build ---
  k_zero<<<128, 256, 0, stream>>>(rowCnt, N);
  k_hist_row<<<(E + 255) / 256, 256, 0, stream>>>(dst, E, rowCnt);
  k_scan_part<<<256, 256, 0, stream>>>(rowCnt, N, thrPre, blkSum);
  k_scan_mid<<<1, 256, 0, stream>>>(blkSum, 256, N, blkOff, rowStart);
  k_scan_fin<<<256, 256, 0, stream>>>(rowCnt, N, thrPre, blkOff, rowStart, rowCur);
  k_place_row<<<(E + 255) / 256, 256, 0, stream>>>(etype, src, dst, rowCur, epk, E);

  const dim3 blk(256);
  const int gm = (N + 127) / 128;
  const dim3 gseg((N + 15) / 16);

  // input projection: x0 = tanh(featsb @ W_in + b_in)
  gemm_stream<64, 64, 4><<<dim3(gm, 1), blk, 0, stream>>>(
      featsb, nullptr, wt_in, b_in, xb0, nullptr, N, HID, 1);

  for (int l = 0; l < NL; l++) {
    const __bf16* xin = (l & 1) ? xb1 : xb0;
    __bf16* xout = (l & 1) ? xb0 : xb1;

    // pass 0: Z = xin @ [W_0..3 | W_loop]  (N x 640)
    gemm_stream<128, 128, 4><<<dim3(gm, 5), blk, 0, stream>>>(
        xin, nullptr, wt_z0 + (size_t)l * 5 * TS, nullptr, Z, nullptr, N, 640, 0);
    // seg0: msg = b + Z_self + sum(r<4) edges
    seg_sum<<<gseg, blk, 0, stream>>>(Z, rowStart, epk, b_rel + (size_t)l * HID,
                                      msgb, N, 0, 640, 512);
    // pass 1: Z = xin @ [W_4..7]  (N x 512)
    gemm_stream<128, 128, 4><<<dim3(gm, 4), blk, 0, stream>>>(
        xin, nullptr, wt_z1 + (size_t)l * 4 * TS, nullptr, Z, nullptr, N, 512, 0);
    // seg1: msg += sum(r>=4) edges
    seg_sum<<<gseg, blk, 0, stream>>>(Z, rowStart, epk, nullptr,
                                      msgb, N, 4, 512, -1);

    // mid = tanh([x | msg] @ W_u1[l] + b_u1[l])   (mid aliases Z; Z is dead)
    gemm_stream<256, 128, 2><<<dim3(gm, 2), blk, 0, stream>>>(
        xin, msgb, wt_u1 + (size_t)l * 256 * 256, b_u1 + (size_t)l * 256,
        mid, nullptr, N, 256, 1);

    // x' = tanh([x | mid] @ W_u2[l] + b_u2[l]); last layer -> f32 d_out
    gemm_stream<384, 128, 1><<<dim3(gm, 1), blk, 0, stream>>>(
        xin, mid, wt_u2 + (size_t)l * HID * 384, b_u2 + (size_t)l * HID,
        (l == NL - 1) ? nullptr : xout,
        (l == NL - 1) ? (float*)d_out : nullptr,
        N, HID, 1);
  }
}

// Round 3
// 3806.826 us; speedup vs baseline: 1.1128x; 1.0094x over previous
//
#include <hip/hip_runtime.h>
#include <cstddef>

// ---------------------------------------------------------------------------
// RelGraphConv GNN, 10 layers. Round 11: 512-thread streaming GEMM + prefetch.
//   R10 post-mortem: removing barriers was neutral -> GEMMs are load-latency
//   bound (U1: 8 waves/CU cap from 66KB LDS, ~6 loads in flight, MfmaUtil 4%).
//   R11: 512-thread blocks with 256-row tiles double resident waves/CU at the
//   same LDS footprint (U1 8->16 waves, U2 4->8); explicit 1-deep A-fragment
//   register prefetch keeps 4 loads always in flight per wave; A(0) loads
//   issue before the B-stage barrier.
// Z buffer (128 MB) aliases mid (dead during Z/segsum); ws ~214 MB.
// N=100000, E=600000, F=64, H=128, R=8.
// ---------------------------------------------------------------------------

#define HID 128
#define NREL 8
#define NL 10

typedef __attribute__((ext_vector_type(8))) __bf16 bf16x8;
typedef __attribute__((ext_vector_type(4))) float f32x4;

// --- batched transpose + f32->bf16: tile z: W[zi][K][Nc] -> Wt[zo][Nc][K] ---
__global__ __launch_bounds__(256) void k_transpose(const float* __restrict__ W,
                                                   __bf16* __restrict__ Wt,
                                                   int K, int Nc,
                                                   int inDiv, int inScale, int inOff,
                                                   int outDiv, int outScale, int outOff) {
  __shared__ float t[32][33];
  int z = blockIdx.z;
  int zi = (z / inDiv) * inScale + (z % inDiv) + inOff;
  int zo = (z / outDiv) * outScale + (z % outDiv) + outOff;
  const float* Wz = W + (size_t)zi * K * Nc;
  __bf16* Wtz = Wt + (size_t)zo * K * Nc;
  int n0 = blockIdx.x * 32, k0 = blockIdx.y * 32;
#pragma unroll
  for (int i = 0; i < 4; i++) {
    int k = k0 + threadIdx.y + i * 8;
    int n = n0 + threadIdx.x;
    t[threadIdx.y + i * 8][threadIdx.x] = Wz[(size_t)k * Nc + n];
  }
  __syncthreads();
#pragma unroll
  for (int i = 0; i < 4; i++) {
    int n = n0 + threadIdx.y + i * 8;
    int k = k0 + threadIdx.x;
    Wtz[(size_t)n * K + k] = (__bf16)t[threadIdx.x][threadIdx.y + i * 8];
  }
}

// --- f32 -> bf16 elementwise (n4 = count/4) ---
__global__ __launch_bounds__(256) void k_cvt(const float* __restrict__ x,
                                             __bf16* __restrict__ y, int n4) {
  int i = blockIdx.x * 256 + threadIdx.x;
  if (i < n4) {
    float4 f = ((const float4*)x)[i];
    __bf16 o[4] = {(__bf16)f.x, (__bf16)f.y, (__bf16)f.z, (__bf16)f.w};
    *(uint2*)(y + (size_t)i * 4) = *(uint2*)o;
  }
}

// ===================== dst-CSR build (once per launch) ======================
__global__ __launch_bounds__(256) void k_zero(int* __restrict__ p, int n) {
  for (int i = blockIdx.x * 256 + threadIdx.x; i < n; i += gridDim.x * 256) p[i] = 0;
}

__global__ __launch_bounds__(256) void k_hist_row(const int* __restrict__ dst,
                                                  int E, int* __restrict__ rowCnt) {
  int e = blockIdx.x * 256 + threadIdx.x;
  if (e < E) atomicAdd(&rowCnt[dst[e]], 1);
}

// --- hierarchical prefix scan over rowCnt[0..nb) ---------------------------
__global__ __launch_bounds__(256) void k_scan_part(const int* __restrict__ rowCnt,
                                                   int nb, int* __restrict__ thrPre,
                                                   int* __restrict__ blkSum) {
  __shared__ int sdata[256];
  int tid = threadIdx.x;
  int gtid = blockIdx.x * 256 + tid;
  int tot = gridDim.x * 256;
  int chunk = (nb + tot - 1) / tot;
  int lo = gtid * chunk, hi = min(nb, lo + chunk);
  int s = 0;
  for (int i = lo; i < hi; i++) s += rowCnt[i];
  sdata[tid] = s;
  __syncthreads();
#pragma unroll
  for (int off = 1; off < 256; off <<= 1) {
    int t = (tid >= off) ? sdata[tid - off] : 0;
    __syncthreads();
    sdata[tid] += t;
    __syncthreads();
  }
  thrPre[gtid] = sdata[tid] - s;
  if (tid == 255) blkSum[blockIdx.x] = sdata[255];
}

__global__ __launch_bounds__(256) void k_scan_mid(const int* __restrict__ blkSum,
                                                  int nblk, int nb,
                                                  int* __restrict__ blkOff,
                                                  int* __restrict__ rowStart) {
  __shared__ int part[256];
  int tid = threadIdx.x;
  part[tid] = (tid < nblk) ? blkSum[tid] : 0;
  __syncthreads();
  if (tid == 0) {
    int a = 0;
    for (int i = 0; i < nblk; i++) { int v = part[i]; part[i] = a; a += v; }
    rowStart[nb] = a;
  }
  __syncthreads();
  if (tid < nblk) blkOff[tid] = part[tid];
}

__global__ __launch_bounds__(256) void k_scan_fin(const int* __restrict__ rowCnt,
                                                  int nb,
                                                  const int* __restrict__ thrPre,
                                                  const int* __restrict__ blkOff,
                                                  int* __restrict__ rowStart,
                                                  int* __restrict__ rowCur) {
  int tid = threadIdx.x;
  int gtid = blockIdx.x * 256 + tid;
  int tot = gridDim.x * 256;
  int chunk = (nb + tot - 1) / tot;
  int lo = gtid * chunk, hi = min(nb, lo + chunk);
  int run = blkOff[blockIdx.x] + thrPre[gtid];
  for (int i = lo; i < hi; i++) {
    rowStart[i] = run;
    rowCur[i] = run;
    run += rowCnt[i];
  }
}

// pack: src (17 bits) | etype << 17
__global__ __launch_bounds__(256) void k_place_row(const int* __restrict__ et,
                                                   const int* __restrict__ src,
                                                   const int* __restrict__ dst,
                                                   int* __restrict__ rowCur,
                                                   int* __restrict__ epk, int E) {
  int e = blockIdx.x * 256 + threadIdx.x;
  if (e < E) {
    int p = atomicAdd(&rowCur[dst[e]], 1);
    epk[p] = src[e] | (et[e] << 17);
  }
}

// ========================= CSR segment-sum kernel ===========================
__global__ __launch_bounds__(256) void seg_sum(
    const __bf16* __restrict__ Z, const int* __restrict__ rowStart,
    const int* __restrict__ epk, const float* __restrict__ b_rel_l,
    __bf16* __restrict__ msgb, int N, int relBase, int zW, int selfCol) {
  int t16 = threadIdx.x & 15;
  int d = blockIdx.x * 16 + (threadIdx.x >> 4);
  if (d >= N) return;

  float acc[8];
  if (selfCol >= 0) {
    bf16x8 sv = *(const bf16x8*)(Z + (size_t)d * zW + selfCol + t16 * 8);
#pragma unroll
    for (int z = 0; z < 8; z++) acc[z] = (float)sv[z] + b_rel_l[t16 * 8 + z];
  } else {
    bf16x8 mv = *(const bf16x8*)(msgb + (size_t)d * HID + t16 * 8);
#pragma unroll
    for (int z = 0; z < 8; z++) acc[z] = (float)mv[z];
  }

  int lo = rowStart[d], hi = rowStart[d + 1];
  for (int e = lo; e < hi; e++) {
    int p = epk[e];
    int rr = (p >> 17) - relBase;
    if ((unsigned)rr < 4u) {
      bf16x8 v = *(const bf16x8*)(Z + (size_t)(p & 0x1FFFF) * zW + rr * HID + t16 * 8);
#pragma unroll
      for (int z = 0; z < 8; z++) acc[z] += (float)v[z];
    }
  }

  bf16x8 o;
#pragma unroll
  for (int z = 0; z < 8; z++) o[z] = (__bf16)acc[z];
  *(bf16x8*)(msgb + (size_t)d * HID + t16 * 8) = o;
}

// ---------------------------------------------------------------------------
// Streaming bf16 MFMA GEMM: C = act(concat(A0,A1) @ B + bias)
//   512 threads, 256-row x 128-col C tile, 8 waves (4 row-groups x 2 col).
//   B column-tile staged in LDS once (one barrier); A streamed directly
//   global -> VGPR with explicit 1-deep prefetch; compile-time K loop.
// ---------------------------------------------------------------------------
template <int K, int K0, int MINW>
__global__ __launch_bounds__(512, MINW) void gemm_stream(
    const __bf16* __restrict__ A0, const __bf16* __restrict__ A1,
    const __bf16* __restrict__ Bt, const float* __restrict__ bias,
    __bf16* __restrict__ Cb, float* __restrict__ Cf,
    int M, int Nc, int act) {
  constexpr int PK = K + 8;
  constexpr int K1 = K - K0;
  constexpr int NK0 = K0 / 32;
  constexpr int NK = K / 32;
  __shared__ __bf16 Bs[128][PK];

  const int tid = threadIdx.x;
  const int m0 = blockIdx.x * 256;
  const int bn0 = blockIdx.y * 128;

  // --- stage B column-tile: 128 rows (= output cols) x K, 16B per thread ---
  {
    constexpr int CH = 128 * K / 8;   // 16B chunks
#pragma unroll
    for (int c0 = 0; c0 < CH; c0 += 512) {
      int c = c0 + tid;
      int row = c / (K / 8);
      int kc = (c % (K / 8)) * 8;
      bf16x8 v = *(const bf16x8*)(Bt + (size_t)(bn0 + row) * K + kc);
      *(bf16x8*)(&Bs[row][kc]) = v;
    }
  }

  const int lane = tid & 63;
  const int w = tid >> 6;             // 0..7
  const int ml = lane & 15, q = lane >> 4;
  const int wr = (w >> 1) * 64;       // 0,64,128,192
  const int wc = (w & 1) * 64;        // 0,64

  // per-i clamped row base pointers (q*8 folded in)
  const __bf16* pA0[4];
  const __bf16* pA1[4];
#pragma unroll
  for (int i = 0; i < 4; i++) {
    int row = m0 + wr + i * 16 + ml;
    int rc = row < M ? row : M - 1;
    pA0[i] = A0 + (size_t)rc * K0 + q * 8;
    if (K1 > 0) pA1[i] = A1 + (size_t)rc * K1 + q * 8;
    else pA1[i] = pA0[i];
  }

  f32x4 acc[4][4];
#pragma unroll
  for (int i = 0; i < 4; i++)
#pragma unroll
    for (int j = 0; j < 4; j++)
#pragma unroll
      for (int r = 0; r < 4; r++) acc[i][j][r] = 0.f;

  // prefetch A(kk=0) before the barrier: HBM latency hides under B-stage
  bf16x8 afc[4], afn[4];
#pragma unroll
  for (int i = 0; i < 4; i++) afc[i] = *(const bf16x8*)(pA0[i]);

  __syncthreads();  // B ready

#pragma unroll
  for (int kk = 0; kk < NK; kk++) {
    // issue next A loads first (1-deep prefetch)
    if (kk + 1 < NK) {
      if (kk + 1 < NK0) {
#pragma unroll
        for (int i = 0; i < 4; i++)
          afn[i] = *(const bf16x8*)(pA0[i] + (kk + 1) * 32);
      } else {
#pragma unroll
        for (int i = 0; i < 4; i++)
          afn[i] = *(const bf16x8*)(pA1[i] + (kk + 1 - NK0) * 32);
      }
    }
    bf16x8 bfr[4];
#pragma unroll
    for (int j = 0; j < 4; j++)
      bfr[j] = *(const bf16x8*)(&Bs[wc + j * 16 + ml][kk * 32 + q * 8]);
#pragma unroll
    for (int i = 0; i < 4; i++)
#pragma unroll
      for (int j = 0; j < 4; j++)
        acc[i][j] = __builtin_amdgcn_mfma_f32_16x16x32_bf16(afc[i], bfr[j],
                                                            acc[i][j], 0, 0, 0);
#pragma unroll
    for (int i = 0; i < 4; i++) afc[i] = afn[i];
  }

  // --- epilogue ---
#pragma unroll
  for (int i = 0; i < 4; i++) {
#pragma unroll
    for (int r = 0; r < 4; r++) {
      int grow = m0 + wr + i * 16 + q * 4 + r;
      if (grow >= M) continue;
#pragma unroll
      for (int j = 0; j < 4; j++) {
        int col = bn0 + wc + j * 16 + ml;
        float v = acc[i][j][r];
        if (bias) v += bias[col];
        if (act) v = tanhf(v);
        if (Cb) Cb[(size_t)grow * Nc + col] = (__bf16)v;
        if (Cf) Cf[(size_t)grow * Nc + col] = v;
      }
    }
  }
}

extern "C" void kernel_launch(void* const* d_in, const int* in_sizes, int n_in,
                              void* d_out, int out_size, void* d_ws, size_t ws_size,
                              hipStream_t stream) {
  const float* feats  = (const float*)d_in[0];
  const int*   src    = (const int*)d_in[1];
  const int*   dst    = (const int*)d_in[2];
  const int*   etype  = (const int*)d_in[3];
  const float* W_in   = (const float*)d_in[4];
  const float* b_in   = (const float*)d_in[5];
  const float* W_rel  = (const float*)d_in[6];
  const float* W_loop = (const float*)d_in[7];
  const float* b_rel  = (const float*)d_in[8];
  const float* W_u1   = (const float*)d_in[9];
  const float* b_u1   = (const float*)d_in[10];
  const float* W_u2   = (const float*)d_in[11];
  const float* b_u2   = (const float*)d_in[12];

  const int E = in_sizes[1];
  const int N = in_sizes[0] / 64;
  const int TS = HID * HID;

  // --- workspace layout (~214 MB) ---
  __bf16* xb0  = (__bf16*)d_ws;                       // N*128
  __bf16* xb1  = xb0 + (size_t)N * HID;               // N*128
  __bf16* msgb = xb1 + (size_t)N * HID;               // N*128
  __bf16* U    = msgb + (size_t)N * HID;              // N*640 (Z | mid | featsb)
  __bf16* Z    = U;
  __bf16* mid  = U;
  __bf16* featsb = U;
  __bf16* wt_in = U + (size_t)N * 640;                // [128][64]
  __bf16* wt_z0 = wt_in + 128 * 64;                   // [10][5][128][128]
  __bf16* wt_z1 = wt_z0 + (size_t)10 * 5 * TS;        // [10][4][128][128]
  __bf16* wt_u1 = wt_z1 + (size_t)10 * 4 * TS;        // [10][256][256]
  __bf16* wt_u2 = wt_u1 + (size_t)10 * 256 * 256;     // [10][128][384]
  int* rowCnt   = (int*)(wt_u2 + (size_t)10 * 128 * 384); // N
  int* rowStart = rowCnt + N;                         // N+1
  int* rowCur   = rowStart + N + 1;                   // N
  int* epk      = rowCur + N;                         // E
  int* thrPre   = epk + E;                            // 256*256
  int* blkSum   = thrPre + 256 * 256;                 // 256
  int* blkOff   = blkSum + 256;                       // 256

  // --- weight transpose+convert ---
  k_transpose<<<dim3(4, 2, 1), dim3(32, 8), 0, stream>>>(W_in, wt_in, 64, 128,
                                                         1, 1, 0, 1, 1, 0);
  k_transpose<<<dim3(4, 4, 40), dim3(32, 8), 0, stream>>>(W_rel, wt_z0, 128, 128,
                                                          4, 8, 0, 4, 5, 0);
  k_transpose<<<dim3(4, 4, 40), dim3(32, 8), 0, stream>>>(W_rel, wt_z1, 128, 128,
                                                          4, 8, 4, 4, 4, 0);
  k_transpose<<<dim3(4, 4, 10), dim3(32, 8), 0, stream>>>(W_loop, wt_z0, 128, 128,
                                                          1, 1, 0, 1, 5, 4);
  k_transpose<<<dim3(8, 8, 10), dim3(32, 8), 0, stream>>>(W_u1, wt_u1, 256, 256,
                                                          1, 1, 0, 1, 1, 0);
  k_transpose<<<dim3(4, 12, 10), dim3(32, 8), 0, stream>>>(W_u2, wt_u2, 384, 128,
                                                           1, 1, 0, 1, 1, 0);
  k_cvt<<<(N * 64 / 4 + 255) / 256, 256, 0, stream>>>(feats, featsb, N * 64 / 4);

  // --- dst-CSR build ---
  k_zero<<<128, 256, 0, stream>>>(rowCnt, N);
  k_hist_row<<<(E + 255) / 256, 256, 0, stream>>>(dst, E, rowCnt);
  k_scan_part<<<256, 256, 0, stream>>>(rowCnt, N, thrPre, blkSum);
  k_scan_mid<<<1, 256, 0, stream>>>(blkSum, 256, N, blkOff, rowStart);
  k_scan_fin<<<256, 256, 0, stream>>>(rowCnt, N, thrPre, blkOff, rowStart, rowCur);
  k_place_row<<<(E + 255) / 256, 256, 0, stream>>>(etype, src, dst, rowCur, epk, E);

  const dim3 blk(512);
  const int gm = (N + 255) / 256;
  const dim3 gseg((N + 15) / 16);

  // input projection: x0 = tanh(featsb @ W_in + b_in)
  gemm_stream<64, 64, 4><<<dim3(gm, 1), blk, 0, stream>>>(
      featsb, nullptr, wt_in, b_in, xb0, nullptr, N, HID, 1);

  for (int l = 0; l < NL; l++) {
    const __bf16* xin = (l & 1) ? xb1 : xb0;
    __bf16* xout = (l & 1) ? xb0 : xb1;

    // pass 0: Z = xin @ [W_0..3 | W_loop]  (N x 640)
    gemm_stream<128, 128, 4><<<dim3(gm, 5), blk, 0, stream>>>(
        xin, nullptr, wt_z0 + (size_t)l * 5 * TS, nullptr, Z, nullptr, N, 640, 0);
    // seg0: msg = b + Z_self + sum(r<4) edges
    seg_sum<<<gseg, dim3(256), 0, stream>>>(Z, rowStart, epk,
                                            b_rel + (size_t)l * HID,
                                            msgb, N, 0, 640, 512);
    // pass 1: Z = xin @ [W_4..7]  (N x 512)
    gemm_stream<128, 128, 4><<<dim3(gm, 4), blk, 0, stream>>>(
        xin, nullptr, wt_z1 + (size_t)l * 4 * TS, nullptr, Z, nullptr, N, 512, 0);
    // seg1: msg += sum(r>=4) edges
    seg_sum<<<gseg, dim3(256), 0, stream>>>(Z, rowStart, epk, nullptr,
                                            msgb, N, 4, 512, -1);

    // mid = tanh([x | msg] @ W_u1[l] + b_u1[l])   (mid aliases Z; Z is dead)
    gemm_stream<256, 128, 4><<<dim3(gm, 2), blk, 0, stream>>>(
        xin, msgb, wt_u1 + (size_t)l * 256 * 256, b_u1 + (size_t)l * 256,
        mid, nullptr, N, 256, 1);

    // x' = tanh([x | mid] @ W_u2[l] + b_u2[l]); last layer -> f32 d_out
    gemm_stream<384, 128, 2><<<dim3(gm, 1), blk, 0, stream>>>(
        xin, mid, wt_u2 + (size_t)l * HID * 384, b_u2 + (size_t)l * HID,
        (l == NL - 1) ? nullptr : xout,
        (l == NL - 1) ? (float*)d_out : nullptr,
        N, HID, 1);
  }
}

// Round 4
// 2665.214 us; speedup vs baseline: 1.5895x; 1.4283x over previous
//
#include <hip/hip_runtime.h>
#include <cstddef>

// ---------------------------------------------------------------------------
// RelGraphConv GNN, 10 layers. Round 12: global_load_lds DMA GEMM (m97-style).
//   R1-R3 post-mortem: all GEMM variants pinned at ~0.9-1.1 TB/s regardless of
//   occupancy/barriers/prefetch. Little's law: per-wave VGPR loads hold only
//   64 B in flight/wave -> ~1 KB/CU -> ~1 TB/s ceiling at ~900 cy HBM latency.
//   Fix: stage A and B K-tiles via __builtin_amdgcn_global_load_lds (async
//   DMA, 16 KB/block in flight), double-buffered BK=32, stage(k+1) issued
//   before compute(k), ONE __syncthreads per K-step (implicit vmcnt(0) drain).
//   Also: tanhf (~70% of VALUBusy) -> exp2-based fast_tanh (8 ops).
// Z buffer (128 MB) aliases mid (dead during Z/segsum); ws ~214 MB.
// N=100000, E=600000, F=64, H=128, R=8.
// ---------------------------------------------------------------------------

#define HID 128
#define NREL 8
#define NL 10

typedef __attribute__((ext_vector_type(8))) __bf16 bf16x8;
typedef __attribute__((ext_vector_type(4))) float f32x4;

__device__ __forceinline__ float fast_tanh(float x) {
  // tanh(x) = (e^2x - 1)/(e^2x + 1); e^2x = 2^(2x*log2e). Clamp |x|<=10
  // (tanh(10) = 1 - 4e-9, far below bf16 quantum). rel err ~1e-6.
  float cx = fminf(fmaxf(x, -10.f), 10.f);
  float z = exp2f(cx * 2.8853900817779268f);
  return (z - 1.f) * __builtin_amdgcn_rcpf(z + 1.f);
}

// --- batched transpose + f32->bf16: tile z: W[zi][K][Nc] -> Wt[zo][Nc][K] ---
__global__ __launch_bounds__(256) void k_transpose(const float* __restrict__ W,
                                                   __bf16* __restrict__ Wt,
                                                   int K, int Nc,
                                                   int inDiv, int inScale, int inOff,
                                                   int outDiv, int outScale, int outOff) {
  __shared__ float t[32][33];
  int z = blockIdx.z;
  int zi = (z / inDiv) * inScale + (z % inDiv) + inOff;
  int zo = (z / outDiv) * outScale + (z % outDiv) + outOff;
  const float* Wz = W + (size_t)zi * K * Nc;
  __bf16* Wtz = Wt + (size_t)zo * K * Nc;
  int n0 = blockIdx.x * 32, k0 = blockIdx.y * 32;
#pragma unroll
  for (int i = 0; i < 4; i++) {
    int k = k0 + threadIdx.y + i * 8;
    int n = n0 + threadIdx.x;
    t[threadIdx.y + i * 8][threadIdx.x] = Wz[(size_t)k * Nc + n];
  }
  __syncthreads();
#pragma unroll
  for (int i = 0; i < 4; i++) {
    int n = n0 + threadIdx.y + i * 8;
    int k = k0 + threadIdx.x;
    Wtz[(size_t)n * K + k] = (__bf16)t[threadIdx.x][threadIdx.y + i * 8];
  }
}

// --- f32 -> bf16 elementwise (n4 = count/4) ---
__global__ __launch_bounds__(256) void k_cvt(const float* __restrict__ x,
                                             __bf16* __restrict__ y, int n4) {
  int i = blockIdx.x * 256 + threadIdx.x;
  if (i < n4) {
    float4 f = ((const float4*)x)[i];
    __bf16 o[4] = {(__bf16)f.x, (__bf16)f.y, (__bf16)f.z, (__bf16)f.w};
    *(uint2*)(y + (size_t)i * 4) = *(uint2*)o;
  }
}

// ===================== dst-CSR build (once per launch) ======================
__global__ __launch_bounds__(256) void k_zero(int* __restrict__ p, int n) {
  for (int i = blockIdx.x * 256 + threadIdx.x; i < n; i += gridDim.x * 256) p[i] = 0;
}

__global__ __launch_bounds__(256) void k_hist_row(const int* __restrict__ dst,
                                                  int E, int* __restrict__ rowCnt) {
  int e = blockIdx.x * 256 + threadIdx.x;
  if (e < E) atomicAdd(&rowCnt[dst[e]], 1);
}

// --- hierarchical prefix scan over rowCnt[0..nb) ---------------------------
__global__ __launch_bounds__(256) void k_scan_part(const int* __restrict__ rowCnt,
                                                   int nb, int* __restrict__ thrPre,
                                                   int* __restrict__ blkSum) {
  __shared__ int sdata[256];
  int tid = threadIdx.x;
  int gtid = blockIdx.x * 256 + tid;
  int tot = gridDim.x * 256;
  int chunk = (nb + tot - 1) / tot;
  int lo = gtid * chunk, hi = min(nb, lo + chunk);
  int s = 0;
  for (int i = lo; i < hi; i++) s += rowCnt[i];
  sdata[tid] = s;
  __syncthreads();
#pragma unroll
  for (int off = 1; off < 256; off <<= 1) {
    int t = (tid >= off) ? sdata[tid - off] : 0;
    __syncthreads();
    sdata[tid] += t;
    __syncthreads();
  }
  thrPre[gtid] = sdata[tid] - s;
  if (tid == 255) blkSum[blockIdx.x] = sdata[255];
}

__global__ __launch_bounds__(256) void k_scan_mid(const int* __restrict__ blkSum,
                                                  int nblk, int nb,
                                                  int* __restrict__ blkOff,
                                                  int* __restrict__ rowStart) {
  __shared__ int part[256];
  int tid = threadIdx.x;
  part[tid] = (tid < nblk) ? blkSum[tid] : 0;
  __syncthreads();
  if (tid == 0) {
    int a = 0;
    for (int i = 0; i < nblk; i++) { int v = part[i]; part[i] = a; a += v; }
    rowStart[nb] = a;
  }
  __syncthreads();
  if (tid < nblk) blkOff[tid] = part[tid];
}

__global__ __launch_bounds__(256) void k_scan_fin(const int* __restrict__ rowCnt,
                                                  int nb,
                                                  const int* __restrict__ thrPre,
                                                  const int* __restrict__ blkOff,
                                                  int* __restrict__ rowStart,
                                                  int* __restrict__ rowCur) {
  int tid = threadIdx.x;
  int gtid = blockIdx.x * 256 + tid;
  int tot = gridDim.x * 256;
  int chunk = (nb + tot - 1) / tot;
  int lo = gtid * chunk, hi = min(nb, lo + chunk);
  int run = blkOff[blockIdx.x] + thrPre[gtid];
  for (int i = lo; i < hi; i++) {
    rowStart[i] = run;
    rowCur[i] = run;
    run += rowCnt[i];
  }
}

// pack: src (17 bits) | etype << 17
__global__ __launch_bounds__(256) void k_place_row(const int* __restrict__ et,
                                                   const int* __restrict__ src,
                                                   const int* __restrict__ dst,
                                                   int* __restrict__ rowCur,
                                                   int* __restrict__ epk, int E) {
  int e = blockIdx.x * 256 + threadIdx.x;
  if (e < E) {
    int p = atomicAdd(&rowCur[dst[e]], 1);
    epk[p] = src[e] | (et[e] << 17);
  }
}

// ========================= CSR segment-sum kernel ===========================
__global__ __launch_bounds__(256) void seg_sum(
    const __bf16* __restrict__ Z, const int* __restrict__ rowStart,
    const int* __restrict__ epk, const float* __restrict__ b_rel_l,
    __bf16* __restrict__ msgb, int N, int relBase, int zW, int selfCol) {
  int t16 = threadIdx.x & 15;
  int d = blockIdx.x * 16 + (threadIdx.x >> 4);
  if (d >= N) return;

  float acc[8];
  if (selfCol >= 0) {
    bf16x8 sv = *(const bf16x8*)(Z + (size_t)d * zW + selfCol + t16 * 8);
#pragma unroll
    for (int z = 0; z < 8; z++) acc[z] = (float)sv[z] + b_rel_l[t16 * 8 + z];
  } else {
    bf16x8 mv = *(const bf16x8*)(msgb + (size_t)d * HID + t16 * 8);
#pragma unroll
    for (int z = 0; z < 8; z++) acc[z] = (float)mv[z];
  }

  int lo = rowStart[d], hi = rowStart[d + 1];
  for (int e = lo; e < hi; e++) {
    int p = epk[e];
    int rr = (p >> 17) - relBase;
    if ((unsigned)rr < 4u) {
      bf16x8 v = *(const bf16x8*)(Z + (size_t)(p & 0x1FFFF) * zW + rr * HID + t16 * 8);
#pragma unroll
      for (int z = 0; z < 8; z++) acc[z] += (float)v[z];
    }
  }

  bf16x8 o;
#pragma unroll
  for (int z = 0; z < 8; z++) o[z] = (__bf16)acc[z];
  *(bf16x8*)(msgb + (size_t)d * HID + t16 * 8) = o;
}

// ---------------------------------------------------------------------------
// DMA-staged bf16 MFMA GEMM: C = act(concat(A0,A1) @ B + bias)
//   m97/T3-minimum structure: 128x128 C-tile, 256 threads (4 waves),
//   BK=32 double-buffered As/Bs staged via global_load_lds (16B DMA, linear
//   LDS), stage(k+1) issued before compute(k), one __syncthreads per step.
//   Per buffer: 128 rows x 32 k x 2B = 8 KB = 512 x 16B chunks; each wave
//   issues 2 DMA calls per operand (64 lanes x 16B = 1 KB per call).
// ---------------------------------------------------------------------------
template <int K, int K0, int MINW>
__global__ __launch_bounds__(256, MINW) void gemm_lds(
    const __bf16* __restrict__ A0, const __bf16* __restrict__ A1,
    const __bf16* __restrict__ Bt, const float* __restrict__ bias,
    __bf16* __restrict__ Cb, float* __restrict__ Cf,
    int M, int Nc, int act) {
  constexpr int NS = K / 32;    // K-steps
  constexpr int NS0 = K0 / 32;  // steps sourced from A0
  constexpr int K1 = (K - K0) > 0 ? (K - K0) : 1;
  __shared__ __bf16 As[2][128][32];
  __shared__ __bf16 Bs[2][128][32];

  const int tid = threadIdx.x;
  const int m0 = blockIdx.x * 128;
  const int bn0 = blockIdx.y * 128;
  const int w = tid >> 6;
  const int lane = tid & 63;

  // DMA chunk geometry: chunk c (16B) -> row c>>2, 16B-slot c&3.
  const int cA = w * 128 + lane;          // this wave's call-0 chunk
  const int r0 = cA >> 2, s0 = cA & 3;
  const int r1 = (cA + 64) >> 2, s1 = (cA + 64) & 3;

  auto stage_step = [&](int b, int ks) {
    // B tile: rows = output cols (stride K)
    {
      const __bf16* g0 = Bt + (size_t)(bn0 + r0) * K + ks * 32 + s0 * 8;
      __builtin_amdgcn_global_load_lds(
          (const __attribute__((address_space(1))) void*)g0,
          (__attribute__((address_space(3))) void*)(&Bs[b][0][0] + (w * 2 + 0) * 512),
          16, 0, 0);
      const __bf16* g1 = Bt + (size_t)(bn0 + r1) * K + ks * 32 + s1 * 8;
      __builtin_amdgcn_global_load_lds(
          (const __attribute__((address_space(1))) void*)g1,
          (__attribute__((address_space(3))) void*)(&Bs[b][0][0] + (w * 2 + 1) * 512),
          16, 0, 0);
    }
    // A tile: concat segment select (wave-uniform per step)
    if (ks < NS0) {
      const __bf16* g0 = A0 + (size_t)(m0 + r0) * K0 + ks * 32 + s0 * 8;
      __builtin_amdgcn_global_load_lds(
          (const __attribute__((address_space(1))) void*)g0,
          (__attribute__((address_space(3))) void*)(&As[b][0][0] + (w * 2 + 0) * 512),
          16, 0, 0);
      const __bf16* g1 = A0 + (size_t)(m0 + r1) * K0 + ks * 32 + s1 * 8;
      __builtin_amdgcn_global_load_lds(
          (const __attribute__((address_space(1))) void*)g1,
          (__attribute__((address_space(3))) void*)(&As[b][0][0] + (w * 2 + 1) * 512),
          16, 0, 0);
    } else {
      const __bf16* g0 = A1 + (size_t)(m0 + r0) * K1 + (ks - NS0) * 32 + s0 * 8;
      __builtin_amdgcn_global_load_lds(
          (const __attribute__((address_space(1))) void*)g0,
          (__attribute__((address_space(3))) void*)(&As[b][0][0] + (w * 2 + 0) * 512),
          16, 0, 0);
      const __bf16* g1 = A1 + (size_t)(m0 + r1) * K1 + (ks - NS0) * 32 + s1 * 8;
      __builtin_amdgcn_global_load_lds(
          (const __attribute__((address_space(1))) void*)g1,
          (__attribute__((address_space(3))) void*)(&As[b][0][0] + (w * 2 + 1) * 512),
          16, 0, 0);
    }
  };

  const int ml = lane & 15, q = lane >> 4;
  const int wr = (w >> 1) * 64, wc = (w & 1) * 64;

  f32x4 acc[4][4];
#pragma unroll
  for (int i = 0; i < 4; i++)
#pragma unroll
    for (int j = 0; j < 4; j++)
#pragma unroll
      for (int r = 0; r < 4; r++) acc[i][j][r] = 0.f;

  stage_step(0, 0);
  __syncthreads();  // implicit vmcnt(0): buffer 0 ready

#pragma unroll
  for (int ks = 0; ks < NS; ks++) {
    const int cur = ks & 1;
    if (ks + 1 < NS) stage_step(cur ^ 1, ks + 1);  // async DMA, in flight
    bf16x8 af[4], bfr[4];
#pragma unroll
    for (int i = 0; i < 4; i++)
      af[i] = *(const bf16x8*)(&As[cur][wr + i * 16 + ml][q * 8]);
#pragma unroll
    for (int j = 0; j < 4; j++)
      bfr[j] = *(const bf16x8*)(&Bs[cur][wc + j * 16 + ml][q * 8]);
#pragma unroll
    for (int i = 0; i < 4; i++)
#pragma unroll
      for (int j = 0; j < 4; j++)
        acc[i][j] = __builtin_amdgcn_mfma_f32_16x16x32_bf16(af[i], bfr[j],
                                                            acc[i][j], 0, 0, 0);
    __syncthreads();  // drains stage(ks+1) DMA; protects buf reuse
  }

  // --- epilogue ---
#pragma unroll
  for (int i = 0; i < 4; i++) {
#pragma unroll
    for (int r = 0; r < 4; r++) {
      int grow = m0 + wr + i * 16 + q * 4 + r;
      if (grow >= M) continue;
#pragma unroll
      for (int j = 0; j < 4; j++) {
        int col = bn0 + wc + j * 16 + ml;
        float v = acc[i][j][r];
        if (bias) v += bias[col];
        if (act) v = fast_tanh(v);
        if (Cb) Cb[(size_t)grow * Nc + col] = (__bf16)v;
        if (Cf) Cf[(size_t)grow * Nc + col] = v;
      }
    }
  }
}

extern "C" void kernel_launch(void* const* d_in, const int* in_sizes, int n_in,
                              void* d_out, int out_size, void* d_ws, size_t ws_size,
                              hipStream_t stream) {
  const float* feats  = (const float*)d_in[0];
  const int*   src    = (const int*)d_in[1];
  const int*   dst    = (const int*)d_in[2];
  const int*   etype  = (const int*)d_in[3];
  const float* W_in   = (const float*)d_in[4];
  const float* b_in   = (const float*)d_in[5];
  const float* W_rel  = (const float*)d_in[6];
  const float* W_loop = (const float*)d_in[7];
  const float* b_rel  = (const float*)d_in[8];
  const float* W_u1   = (const float*)d_in[9];
  const float* b_u1   = (const float*)d_in[10];
  const float* W_u2   = (const float*)d_in[11];
  const float* b_u2   = (const float*)d_in[12];

  const int E = in_sizes[1];
  const int N = in_sizes[0] / 64;
  const int TS = HID * HID;

  // --- workspace layout (~214 MB) ---
  __bf16* xb0  = (__bf16*)d_ws;                       // N*128
  __bf16* xb1  = xb0 + (size_t)N * HID;               // N*128
  __bf16* msgb = xb1 + (size_t)N * HID;               // N*128
  __bf16* U    = msgb + (size_t)N * HID;              // N*640 (Z | mid | featsb)
  __bf16* Z    = U;
  __bf16* mid  = U;
  __bf16* featsb = U;
  __bf16* wt_in = U + (size_t)N * 640;                // [128][64]
  __bf16* wt_z0 = wt_in + 128 * 64;                   // [10][5][128][128]
  __bf16* wt_z1 = wt_z0 + (size_t)10 * 5 * TS;        // [10][4][128][128]
  __bf16* wt_u1 = wt_z1 + (size_t)10 * 4 * TS;        // [10][256][256]
  __bf16* wt_u2 = wt_u1 + (size_t)10 * 256 * 256;     // [10][128][384]
  int* rowCnt   = (int*)(wt_u2 + (size_t)10 * 128 * 384); // N
  int* rowStart = rowCnt + N;                         // N+1
  int* rowCur   = rowStart + N + 1;                   // N
  int* epk      = rowCur + N;                         // E
  int* thrPre   = epk + E;                            // 256*256
  int* blkSum   = thrPre + 256 * 256;                 // 256
  int* blkOff   = blkSum + 256;                       // 256

  // --- weight transpose+convert ---
  k_transpose<<<dim3(4, 2, 1), dim3(32, 8), 0, stream>>>(W_in, wt_in, 64, 128,
                                                         1, 1, 0, 1, 1, 0);
  k_transpose<<<dim3(4, 4, 40), dim3(32, 8), 0, stream>>>(W_rel, wt_z0, 128, 128,
                                                          4, 8, 0, 4, 5, 0);
  k_transpose<<<dim3(4, 4, 40), dim3(32, 8), 0, stream>>>(W_rel, wt_z1, 128, 128,
                                                          4, 8, 4, 4, 4, 0);
  k_transpose<<<dim3(4, 4, 10), dim3(32, 8), 0, stream>>>(W_loop, wt_z0, 128, 128,
                                                          1, 1, 0, 1, 5, 4);
  k_transpose<<<dim3(8, 8, 10), dim3(32, 8), 0, stream>>>(W_u1, wt_u1, 256, 256,
                                                          1, 1, 0, 1, 1, 0);
  k_transpose<<<dim3(4, 12, 10), dim3(32, 8), 0, stream>>>(W_u2, wt_u2, 384, 128,
                                                           1, 1, 0, 1, 1, 0);
  k_cvt<<<(N * 64 / 4 + 255) / 256, 256, 0, stream>>>(feats, featsb, N * 64 / 4);

  // --- dst-CSR build ---
  k_zero<<<128, 256, 0, stream>>>(rowCnt, N);
  k_hist_row<<<(E + 255) / 256, 256, 0, stream>>>(dst, E, rowCnt);
  k_scan_part<<<256, 256, 0, stream>>>(rowCnt, N, thrPre, blkSum);
  k_scan_mid<<<1, 256, 0, stream>>>(blkSum, 256, N, blkOff, rowStart);
  k_scan_fin<<<256, 256, 0, stream>>>(rowCnt, N, thrPre, blkOff, rowStart, rowCur);
  k_place_row<<<(E + 255) / 256, 256, 0, stream>>>(etype, src, dst, rowCur, epk, E);

  const dim3 blk(256);
  const int gm = (N + 127) / 128;
  const dim3 gseg((N + 15) / 16);

  // input projection: x0 = tanh(featsb @ W_in + b_in)
  gemm_lds<64, 64, 2><<<dim3(gm, 1), blk, 0, stream>>>(
      featsb, featsb, wt_in, b_in, xb0, nullptr, N, HID, 1);

  for (int l = 0; l < NL; l++) {
    const __bf16* xin = (l & 1) ? xb1 : xb0;
    __bf16* xout = (l & 1) ? xb0 : xb1;

    // pass 0: Z = xin @ [W_0..3 | W_loop]  (N x 640)
    gemm_lds<128, 128, 2><<<dim3(gm, 5), blk, 0, stream>>>(
        xin, xin, wt_z0 + (size_t)l * 5 * TS, nullptr, Z, nullptr, N, 640, 0);
    // seg0: msg = b + Z_self + sum(r<4) edges
    seg_sum<<<gseg, blk, 0, stream>>>(Z, rowStart, epk, b_rel + (size_t)l * HID,
                                      msgb, N, 0, 640, 512);
    // pass 1: Z = xin @ [W_4..7]  (N x 512)
    gemm_lds<128, 128, 2><<<dim3(gm, 4), blk, 0, stream>>>(
        xin, xin, wt_z1 + (size_t)l * 4 * TS, nullptr, Z, nullptr, N, 512, 0);
    // seg1: msg += sum(r>=4) edges
    seg_sum<<<gseg, blk, 0, stream>>>(Z, rowStart, epk, nullptr,
                                      msgb, N, 4, 512, -1);

    // mid = tanh([x | msg] @ W_u1[l] + b_u1[l])   (mid aliases Z; Z is dead)
    gemm_lds<256, 128, 2><<<dim3(gm, 2), blk, 0, stream>>>(
        xin, msgb, wt_u1 + (size_t)l * 256 * 256, b_u1 + (size_t)l * 256,
        mid, nullptr, N, 256, 1);

    // x' = tanh([x | mid] @ W_u2[l] + b_u2[l]); last layer -> f32 d_out
    gemm_lds<384, 128, 2><<<dim3(gm, 1), blk, 0, stream>>>(
        xin, mid, wt_u2 + (size_t)l * HID * 384, b_u2 + (size_t)l * HID,
        (l == NL - 1) ? nullptr : xout,
        (l == NL - 1) ? (float*)d_out : nullptr,
        N, HID, 1);
  }
}